// Round 3
// baseline (829.830 us; speedup 1.0000x reference)
//
#include <hip/hip_runtime.h>
#include <hip/hip_bf16.h>

// GCN_20332375179669: 2-layer graph attention, B=8 N=2048 H=256 A=64.
// R6 DIAGNOSTIC ROUND: R5's restructure (attn pipeline, qkv prefetch, XCD
// swizzle) was exactly neutral (329->328us) => cost model wrong, and the
// profile top-5 is occluded by 80us harness fills. This round amplifies each
// unique kernel by an idempotent internal rep-loop so each surfaces in the
// top-5 with its own counters:
//   k_fused_front x5, k_qkv_mfma(L1) x16, k_attn<false> x16; layer 2 normal.
// Output remains correct (reps recompute identical values; stores once).
// NEXT ROUND MUST REMOVE THE REP LOOPS.

#define NB 8
#define NN 2048
#define ROWS (NB * NN)
#define MAXD 64   // Binomial(2048,0.01): mean 20.5, sd 4.5 -> ~9.7 sigma

#define FRONT_REPS 5
#define QKV_REPS  16
#define ATTN_REPS 16

typedef float f4 __attribute__((ext_vector_type(4)));
typedef short bf8 __attribute__((ext_vector_type(8)));   // 8 bf16 = one MFMA frag
typedef unsigned short u16;
typedef u16 us4 __attribute__((ext_vector_type(4)));
typedef u16 us8 __attribute__((ext_vector_type(8)));
typedef int i4 __attribute__((ext_vector_type(4)));

__device__ __forceinline__ float sigmoidf_(float x) { return 1.f / (1.f + __expf(-x)); }
__device__ __forceinline__ u16 f2bf(float f) {          // RNE fp32->bf16
    unsigned u = __float_as_uint(f);
    u += 0x7fffu + ((u >> 16) & 1u);
    return (u16)(u >> 16);
}
__device__ __forceinline__ float bf2f(u16 h) {
    return __uint_as_float(((unsigned)h) << 16);
}

// ============================================================== fused front
#define PACK_BLKS 96
#define EMB_BLKS 512

__global__ __launch_bounds__(256) void k_fused_front(
        const int* __restrict__ x, const int* __restrict__ cue,
        const float* __restrict__ adj, const float* __restrict__ emb,
        const float* __restrict__ Wh, const float* __restrict__ bh,
        const float* __restrict__ Wq, const float* __restrict__ Wk,
        const float* __restrict__ Wv,
        u16* __restrict__ hB, u16* __restrict__ Wpt,
        int* __restrict__ deg, int* __restrict__ nbr) {
    __shared__ float As[32 * 64];
    __shared__ float Ws[32 * 128];
    int bid = blockIdx.x;
    int t = threadIdx.x;

    if (bid < PACK_BLKS) {
        int idxp = bid * 256 + t;
#pragma unroll 1
        for (int rep = 0; rep < FRONT_REPS; ++rep) {
#pragma unroll
            for (int r = 0; r < 4; ++r) {
                int i = idxp + r * PACK_BLKS * 256;
                int c = i >> 8, f = i & 255;
                float v;
                if (c < 64)       v = Wq[f * 64 + c];
                else if (c < 128) v = Wk[f * 64 + (c - 64)];
                else              v = Wv[f * 256 + (c - 128)];
                Wpt[i] = f2bf(v);
            }
        }
        return;
    }

    if (bid < PACK_BLKS + EMB_BLKS) {
        // h[64 x 128 tile] = relu(F @ Wh + bh), F = [emb[x], cue]
        int rb2 = bid - PACK_BLKS;
        int v2 = ((rb2 & 7) << 6) + (rb2 >> 3);
        int rt = v2 >> 1, ct = v2 & 1;
        int row0 = rt * 64, col0 = ct * 128;
        int sm = t & 63, skg = t >> 6;
        int swc = (t & 31) * 4, swk = t >> 5;
        int tx = t & 15, ty = t >> 4;
        int xr = x[row0 + sm];
        float cv = (float)cue[row0 + sm];
        const float* er = emb + (size_t)xr * 255;

        float acc[4][8];
#pragma unroll 1
        for (int rep = 0; rep < FRONT_REPS; ++rep) {
#pragma unroll
            for (int i = 0; i < 4; ++i)
#pragma unroll
                for (int j = 0; j < 8; ++j) acc[i][j] = 0.f;

#pragma unroll 1
            for (int kc = 0; kc < 256; kc += 32) {
                int kb = skg * 8;
#pragma unroll
                for (int u = 0; u < 8; ++u) {
                    int f = kc + kb + u;
                    As[(kb + u) * 64 + sm] = (f < 255) ? er[f] : cv;
                }
#pragma unroll
                for (int r = 0; r < 4; ++r) {
                    int kk = swk + r * 8;
                    f4 w = *(const f4*)(Wh + (size_t)(kc + kk) * 256 + col0 + swc);
                    *(f4*)&Ws[kk * 128 + swc] = w;
                }
                __syncthreads();
#pragma unroll
                for (int k = 0; k < 32; ++k) {
                    f4 av = *(f4*)&As[k * 64 + ty * 4];
                    f4 w0 = *(f4*)&Ws[k * 128 + tx * 8];
                    f4 w1 = *(f4*)&Ws[k * 128 + tx * 8 + 4];
                    float a[4] = {av.x, av.y, av.z, av.w};
                    float w[8] = {w0.x, w0.y, w0.z, w0.w, w1.x, w1.y, w1.z, w1.w};
#pragma unroll
                    for (int i = 0; i < 4; ++i)
#pragma unroll
                        for (int j = 0; j < 8; ++j) acc[i][j] += a[i] * w[j];
                }
                __syncthreads();
            }
        }
        f4 b0 = *(const f4*)(bh + col0 + tx * 8);
        f4 b1 = *(const f4*)(bh + col0 + tx * 8 + 4);
        float bb[8] = {b0.x, b0.y, b0.z, b0.w, b1.x, b1.y, b1.z, b1.w};
#pragma unroll
        for (int i = 0; i < 4; ++i) {
            int row = row0 + ty * 4 + i;
            us8 o;
#pragma unroll
            for (int j = 0; j < 8; ++j) o[j] = f2bf(fmaxf(acc[i][j] + bb[j], 0.f));
            *(us8*)(hB + (size_t)row * 256 + col0 + tx * 8) = o;
        }
        return;
    }

    // ---- csr scan (x FRONT_REPS: re-reads 134MB adj per rep -> reports
    // achieved streaming BW directly in this dispatch's hbm_gbps)
    int rb = bid - (PACK_BLKS + EMB_BLKS);
    int row = ((rb & 7) << 11) + (rb >> 3);
    const f4* ar4 = (const f4*)(adj + (size_t)row * NN);
    int* cnt = (int*)As;
    int* nr = nbr + (size_t)row * MAXD;
#pragma unroll 1
    for (int rep = 0; rep < FRONT_REPS; ++rep) {
        if (t == 0) *cnt = 0;
        __syncthreads();
#pragma unroll
        for (int it = 0; it < 2; ++it) {
            int idx = it * 256 + t;
            f4 vv = __builtin_nontemporal_load(ar4 + idx);
            if (vv.x > 0.f) { int p = atomicAdd(cnt, 1); if (p < MAXD) nr[p] = idx * 4 + 0; }
            if (vv.y > 0.f) { int p = atomicAdd(cnt, 1); if (p < MAXD) nr[p] = idx * 4 + 1; }
            if (vv.z > 0.f) { int p = atomicAdd(cnt, 1); if (p < MAXD) nr[p] = idx * 4 + 2; }
            if (vv.w > 0.f) { int p = atomicAdd(cnt, 1); if (p < MAXD) nr[p] = idx * 4 + 3; }
        }
        __syncthreads();
        int c = *cnt; if (c > MAXD) c = MAXD;
        if (t == 0) deg[row] = c;
        if (t < MAXD && t >= c) nr[t] = 0;
        __syncthreads();
    }
}

// ============================================================ qkv bf16 MFMA
template <int REPS>
__global__ __launch_bounds__(256) void k_qkv_mfma(const u16* __restrict__ hB,
                                                  const u16* __restrict__ Wpt,
                                                  float* __restrict__ q,
                                                  u16* __restrict__ kv) {
    __shared__ u16 As[64 * 40];
    __shared__ u16 Bs[128 * 40];
    int t = threadIdx.x;
    int flat = blockIdx.x + blockIdx.y * 3;
    int v = ((flat & 7) * 96) + (flat >> 3);
    int col0 = (v % 3) * 128, row0 = (v / 3) * 64;
    int wave = t >> 6, lane = t & 63;
    int l16 = lane & 15, quad = lane >> 4;

    int ar = t >> 2, ao = (t & 3) * 8;
    int bc = t >> 1, bo = (t & 1) * 16;
    const u16* aP = hB  + (size_t)(row0 + ar) * 256 + ao;
    const u16* bP = Wpt + (size_t)(col0 + bc) * 256 + bo;

    f4 acc[4][2];
#pragma unroll 1
    for (int rep = 0; rep < REPS; ++rep) {
#pragma unroll
        for (int i = 0; i < 4; ++i) { acc[i][0] = (f4){0,0,0,0}; acc[i][1] = (f4){0,0,0,0}; }
        us8 av  = *(const us8*)(aP);
        us8 bv0 = *(const us8*)(bP);
        us8 bv1 = *(const us8*)(bP + 8);
#pragma unroll
        for (int kc = 0; kc < 256; kc += 32) {
            __syncthreads();
            *(us8*)&As[ar * 40 + ao] = av;
            *(us8*)&Bs[bc * 40 + bo] = bv0;
            *(us8*)&Bs[bc * 40 + bo + 8] = bv1;
            __syncthreads();
            if (kc + 32 < 256) {
                av  = *(const us8*)(aP + kc + 32);
                bv0 = *(const us8*)(bP + kc + 32);
                bv1 = *(const us8*)(bP + kc + 40);
            }
            bf8 afr[4], bfr[2];
#pragma unroll
            for (int mt = 0; mt < 4; ++mt)
                afr[mt] = *(bf8*)&As[(mt * 16 + l16) * 40 + quad * 8];
#pragma unroll
            for (int nt = 0; nt < 2; ++nt)
                bfr[nt] = *(bf8*)&Bs[((wave * 2 + nt) * 16 + l16) * 40 + quad * 8];
#pragma unroll
            for (int mt = 0; mt < 4; ++mt)
#pragma unroll
                for (int nt = 0; nt < 2; ++nt)
                    acc[mt][nt] = __builtin_amdgcn_mfma_f32_16x16x32_bf16(
                        afr[mt], bfr[nt], acc[mt][nt], 0, 0, 0);
        }
    }
#pragma unroll
    for (int mt = 0; mt < 4; ++mt)
#pragma unroll
        for (int nt = 0; nt < 2; ++nt) {
            int c = col0 + (wave * 2 + nt) * 16 + l16;
#pragma unroll
            for (int reg = 0; reg < 4; ++reg) {
                int r = row0 + mt * 16 + quad * 4 + reg;
                float val = acc[mt][nt][reg];
                if (c < 64) q[(size_t)r * 64 + c] = val;
                else        kv[(size_t)r * 320 + (c - 64)] = f2bf(val);
            }
        }
}

// ========================================================= sparse attention
template <bool WRITE_OUT, int REPS>
__global__ __launch_bounds__(256) void k_attn(const float* __restrict__ q,
                                              const u16* __restrict__ kv,
                                              const int* __restrict__ deg,
                                              const int* __restrict__ nbr,
                                              const float* __restrict__ gcb,
                                              const float* __restrict__ Wc,
                                              const float* __restrict__ bc,
                                              u16* __restrict__ hB,
                                              float* __restrict__ out) {
    int wave = threadIdx.x >> 6;
    int lane = threadIdx.x & 63;
    int bid = blockIdx.x;
    int vb = ((bid & 7) << 9) + (bid >> 3);
    int row = vb * 4 + wave;
    int d = deg[row];
    int l16 = lane & 15;
    int g = lane >> 4;
    f4 g4 = *(const f4*)(gcb + lane * 4);
    float h0, h1, h2, h3;
    if (d == 0) {
        h0 = sigmoidf_(g4.x); h1 = sigmoidf_(g4.y);
        h2 = sigmoidf_(g4.z); h3 = sigmoidf_(g4.w);
    } else {
        f4 q4 = *(const f4*)(q + (size_t)row * 64 + l16 * 4);
        const int* jl = nbr + (size_t)row * MAXD;
        int bbase = row & ~(NN - 1);  // b * N
        float m, s;
        f4 a;
#pragma unroll 1
        for (int rep = 0; rep < REPS; ++rep) {
            m = -1e30f; s = 0.f;
            a = (f4){0, 0, 0, 0};
            i4 jj = *(const i4*)(jl);
            int jg = (g == 0) ? jj.x : (g == 1) ? jj.y : (g == 2) ? jj.z : jj.w;
            us4 kq = *(const us4*)(kv + (size_t)(bbase + jg) * 320 + l16 * 4);
#pragma unroll 1
            for (int e = 0; e < d; e += 4) {
                int en = (e + 4 < d) ? (e + 4) : 0;
                i4 jjn = *(const i4*)(jl + en);
                int jgn = (g == 0) ? jjn.x : (g == 1) ? jjn.y : (g == 2) ? jjn.z : jjn.w;
                us4 kqn = *(const us4*)(kv + (size_t)(bbase + jgn) * 320 + l16 * 4);
                int ja = (g == 0) ? jj.y : (g == 1) ? jj.x : (g == 2) ? jj.w : jj.z;
                int jb = (g == 0) ? jj.z : (g == 1) ? jj.w : (g == 2) ? jj.x : jj.y;
                int jc = (g == 0) ? jj.w : (g == 1) ? jj.z : (g == 2) ? jj.y : jj.x;
                us4 u0 = *(const us4*)(kv + (size_t)(bbase + jg) * 320 + 64 + lane * 4);
                us4 u1 = *(const us4*)(kv + (size_t)(bbase + ja) * 320 + 64 + lane * 4);
                us4 u2 = *(const us4*)(kv + (size_t)(bbase + jb) * 320 + 64 + lane * 4);
                us4 u3 = *(const us4*)(kv + (size_t)(bbase + jc) * 320 + 64 + lane * 4);
                float p = q4.x * bf2f(kq.x) + q4.y * bf2f(kq.y)
                        + q4.z * bf2f(kq.z) + q4.w * bf2f(kq.w);
                p += __shfl_xor(p, 1); p += __shfl_xor(p, 2);
                p += __shfl_xor(p, 4); p += __shfl_xor(p, 8);
                if (e + g >= d) p = -1e30f;
                float pa = __shfl_xor(p, 16);
                float pb = __shfl_xor(p, 32);
                float pc = __shfl_xor(pa, 32);
                float mx = fmaxf(fmaxf(p, pa), fmaxf(pb, pc));
                float mn = fmaxf(m, mx);
                float scale = __expf(m - mn);
                float w0 = __expf(p - mn),  w1 = __expf(pa - mn);
                float w2 = __expf(pb - mn), w3 = __expf(pc - mn);
                s = s * scale + ((w0 + w1) + (w2 + w3));
                a.x = a.x * scale + w0 * bf2f(u0.x) + w1 * bf2f(u1.x) + w2 * bf2f(u2.x) + w3 * bf2f(u3.x);
                a.y = a.y * scale + w0 * bf2f(u0.y) + w1 * bf2f(u1.y) + w2 * bf2f(u2.y) + w3 * bf2f(u3.y);
                a.z = a.z * scale + w0 * bf2f(u0.z) + w1 * bf2f(u1.z) + w2 * bf2f(u2.z) + w3 * bf2f(u3.z);
                a.w = a.w * scale + w0 * bf2f(u0.w) + w1 * bf2f(u1.w) + w2 * bf2f(u2.w) + w3 * bf2f(u3.w);
                m = mn;
                jj = jjn; jg = jgn; kq = kqn;
            }
        }
        float inv = 1.f / s;
        h0 = sigmoidf_(a.x * inv + g4.x);
        h1 = sigmoidf_(a.y * inv + g4.y);
        h2 = sigmoidf_(a.z * inv + g4.z);
        h3 = sigmoidf_(a.w * inv + g4.w);
    }
    if (!WRITE_OUT) {
        us4 o;
        o.x = f2bf(h0); o.y = f2bf(h1); o.z = f2bf(h2); o.w = f2bf(h3);
        *(us4*)(hB + (size_t)row * 256 + lane * 4) = o;
    } else {
        f4 wc0 = *(const f4*)(Wc + lane * 8);
        f4 wc1 = *(const f4*)(Wc + lane * 8 + 4);
        float pa = h0 * wc0.x + h1 * wc0.z + h2 * wc1.x + h3 * wc1.z;
        float pb = h0 * wc0.y + h1 * wc0.w + h2 * wc1.y + h3 * wc1.w;
#pragma unroll
        for (int off = 32; off; off >>= 1) {
            pa += __shfl_xor(pa, off);
            pb += __shfl_xor(pb, off);
        }
        if (lane == 0) {
            float l0 = pa + bc[0], l1 = pb + bc[1];
            float mx = fmaxf(l0, l1);
            float e0 = __expf(l0 - mx), e1 = __expf(l1 - mx);
            float inv = 1.f / (e0 + e1);
            out[(size_t)row * 2 + 0] = e0 * inv;
            out[(size_t)row * 2 + 1] = e1 * inv;
        }
    }
}

extern "C" void kernel_launch(void* const* d_in, const int* in_sizes, int n_in,
                              void* d_out, int out_size, void* d_ws, size_t ws_size,
                              hipStream_t stream) {
    const int*   x    = (const int*)d_in[0];
    const int*   cue  = (const int*)d_in[1];
    const float* adj  = (const float*)d_in[2];
    const float* emb  = (const float*)d_in[3];
    const float* Wh   = (const float*)d_in[4];
    const float* bh   = (const float*)d_in[5];
    const float* Wq   = (const float*)d_in[6];
    const float* Wk   = (const float*)d_in[7];
    const float* Wv   = (const float*)d_in[8];
    const float* gcb  = (const float*)d_in[9];
    const float* Wc   = (const float*)d_in[10];
    const float* bc   = (const float*)d_in[11];
    float* out = (float*)d_out;

    // workspace carve (~26.3 MB)
    char* w = (char*)d_ws;
    u16*   hB  = (u16*)w;                 w += (size_t)ROWS * 256 * 2;   // 8 MB
    float* q   = (float*)w;               w += (size_t)ROWS * 64 * 4;    // 4 MB
    u16*   kv  = (u16*)w;                 w += (size_t)ROWS * 320 * 2;   // 10 MB
    u16*   Wpt = (u16*)w;                 w += (size_t)384 * 256 * 2;    // 192 KB
    int*   deg = (int*)w;                 w += (size_t)ROWS * 4;         // 64 KB
    int*   nbr = (int*)w;                                                // 4 MB

    // amplified front (x5)
    k_fused_front<<<PACK_BLKS + EMB_BLKS + ROWS, 256, 0, stream>>>(
        x, cue, adj, emb, Wh, bh, Wq, Wk, Wv, hB, Wpt, deg, nbr);
    // layer 1 (amplified x16 each)
    k_qkv_mfma<QKV_REPS><<<dim3(3, ROWS / 64), 256, 0, stream>>>(hB, Wpt, q, kv);
    k_attn<false, ATTN_REPS><<<ROWS / 4, 256, 0, stream>>>(q, kv, deg, nbr, gcb, Wc, bc, hB, out);
    // layer 2 normal (+ fused classifier head)
    k_qkv_mfma<1><<<dim3(3, ROWS / 64), 256, 0, stream>>>(hB, Wpt, q, kv);
    k_attn<true, 1><<<ROWS / 4, 256, 0, stream>>>(q, kv, deg, nbr, gcb, Wc, bc, hB, out);
}

// Round 5
// 323.094 us; speedup vs baseline: 2.5684x; 2.5684x over previous
//
#include <hip/hip_runtime.h>
#include <hip/hip_bf16.h>

// GCN_20332375179669: 2-layer graph attention, B=8 N=2048 H=256 A=64.
// R7: diagnostic (R6) established: attn = 24.2us/dispatch, VALUBusy 83.5%,
// HBM 0.5%, MfmaUtil 0 => VALU-instruction-throughput bound. qkv ~3us,
// front ~30us, and ~245us of the 328us window is harness-fixed (512MiB
// workspace re-poison fills + gaps). This round cuts attn VALU count:
//  - f32 q/k/v in one fused qk[row][384] buffer (kills ~20 bf2f shifts/group;
//    per-batch slab 3MB fits XCD L2; gathers were 0.5% HBM -> headroom)
//  - no online softmax: w = exp2(p), q pre-scaled by log2e in GEMM epilogue
//    (logits O(1), overflow-safe); 1 exp/group via w-exchange instead of 4
//  - direct jl[e+(g^0..3)] loads replace 12 cndmask quad-selects
// R8: round-4 bench was an infra failure (container failed twice, same
// signature as round 0 which passed on resubmit) -> resubmit R7 unchanged.

#define NB 8
#define NN 2048
#define ROWS (NB * NN)
#define MAXD 64   // Binomial(2048,0.01): mean 20.5, sd 4.5 -> ~9.7 sigma

typedef float f4 __attribute__((ext_vector_type(4)));
typedef short bf8 __attribute__((ext_vector_type(8)));   // 8 bf16 = one MFMA frag
typedef unsigned short u16;
typedef u16 us4 __attribute__((ext_vector_type(4)));
typedef u16 us8 __attribute__((ext_vector_type(8)));

__device__ __forceinline__ float sigmoidf_(float x) { return 1.f / (1.f + __expf(-x)); }
__device__ __forceinline__ u16 f2bf(float f) {          // RNE fp32->bf16
    unsigned u = __float_as_uint(f);
    u += 0x7fffu + ((u >> 16) & 1u);
    return (u16)(u >> 16);
}
__device__ __forceinline__ float bf2f(u16 h) {
    return __uint_as_float(((unsigned)h) << 16);
}

// ============================================================== fused front
// bid < 96        : pack Wq|Wk|Wv -> Wpt[c][f] bf16 (transposed, k-contiguous)
// 96 <= bid < 608 : embed GEMM tile (fp32 compute, bf16 h output)
// bid >= 608      : csr row scan (the 134MB adj read = HBM floor)
#define PACK_BLKS 96
#define EMB_BLKS 512

__global__ __launch_bounds__(256) void k_fused_front(
        const int* __restrict__ x, const int* __restrict__ cue,
        const float* __restrict__ adj, const float* __restrict__ emb,
        const float* __restrict__ Wh, const float* __restrict__ bh,
        const float* __restrict__ Wq, const float* __restrict__ Wk,
        const float* __restrict__ Wv,
        u16* __restrict__ hB, u16* __restrict__ Wpt,
        int* __restrict__ deg, int* __restrict__ nbr) {
    __shared__ float As[32 * 64];
    __shared__ float Ws[32 * 128];
    int bid = blockIdx.x;
    int t = threadIdx.x;

    if (bid < PACK_BLKS) {
        // Wpt[c*256 + f] = bf16(W*[f][c]),  c in [0,384), f in [0,256)
        int idxp = bid * 256 + t;
#pragma unroll
        for (int r = 0; r < 4; ++r) {
            int i = idxp + r * PACK_BLKS * 256;
            int c = i >> 8, f = i & 255;
            float v;
            if (c < 64)       v = Wq[f * 64 + c];
            else if (c < 128) v = Wk[f * 64 + (c - 64)];
            else              v = Wv[f * 256 + (c - 128)];
            Wpt[i] = f2bf(v);
        }
        return;
    }

    if (bid < PACK_BLKS + EMB_BLKS) {
        // h[64 x 128 tile] = relu(F @ Wh + bh), F = [emb[x], cue]
        int rb2 = bid - PACK_BLKS;
        int v2 = ((rb2 & 7) << 6) + (rb2 >> 3);
        int rt = v2 >> 1, ct = v2 & 1;
        int row0 = rt * 64, col0 = ct * 128;
        int sm = t & 63, skg = t >> 6;
        int swc = (t & 31) * 4, swk = t >> 5;
        int tx = t & 15, ty = t >> 4;
        int xr = x[row0 + sm];
        float cv = (float)cue[row0 + sm];
        const float* er = emb + (size_t)xr * 255;

        float acc[4][8];
#pragma unroll
        for (int i = 0; i < 4; ++i)
#pragma unroll
            for (int j = 0; j < 8; ++j) acc[i][j] = 0.f;

        for (int kc = 0; kc < 256; kc += 32) {
            int kb = skg * 8;
#pragma unroll
            for (int u = 0; u < 8; ++u) {
                int f = kc + kb + u;
                As[(kb + u) * 64 + sm] = (f < 255) ? er[f] : cv;
            }
#pragma unroll
            for (int r = 0; r < 4; ++r) {
                int kk = swk + r * 8;
                f4 w = *(const f4*)(Wh + (size_t)(kc + kk) * 256 + col0 + swc);
                *(f4*)&Ws[kk * 128 + swc] = w;
            }
            __syncthreads();
#pragma unroll
            for (int k = 0; k < 32; ++k) {
                f4 av = *(f4*)&As[k * 64 + ty * 4];
                f4 w0 = *(f4*)&Ws[k * 128 + tx * 8];
                f4 w1 = *(f4*)&Ws[k * 128 + tx * 8 + 4];
                float a[4] = {av.x, av.y, av.z, av.w};
                float w[8] = {w0.x, w0.y, w0.z, w0.w, w1.x, w1.y, w1.z, w1.w};
#pragma unroll
                for (int i = 0; i < 4; ++i)
#pragma unroll
                    for (int j = 0; j < 8; ++j) acc[i][j] += a[i] * w[j];
            }
            __syncthreads();
        }
        f4 b0 = *(const f4*)(bh + col0 + tx * 8);
        f4 b1 = *(const f4*)(bh + col0 + tx * 8 + 4);
        float bb[8] = {b0.x, b0.y, b0.z, b0.w, b1.x, b1.y, b1.z, b1.w};
#pragma unroll
        for (int i = 0; i < 4; ++i) {
            int row = row0 + ty * 4 + i;
            us8 o;
#pragma unroll
            for (int j = 0; j < 8; ++j) o[j] = f2bf(fmaxf(acc[i][j] + bb[j], 0.f));
            *(us8*)(hB + (size_t)row * 256 + col0 + tx * 8) = o;
        }
        return;
    }

    // ---- csr scan (XCD-batch swizzle: rb%8 = batch, 2048 rows each)
    int rb = bid - (PACK_BLKS + EMB_BLKS);
    int row = ((rb & 7) << 11) + (rb >> 3);
    const f4* ar4 = (const f4*)(adj + (size_t)row * NN);
    int* cnt = (int*)As;
    if (t == 0) *cnt = 0;
    __syncthreads();
    int* nr = nbr + (size_t)row * MAXD;
#pragma unroll
    for (int it = 0; it < 2; ++it) {
        int idx = it * 256 + t;
        f4 vv = __builtin_nontemporal_load(ar4 + idx);
        if (vv.x > 0.f) { int p = atomicAdd(cnt, 1); if (p < MAXD) nr[p] = idx * 4 + 0; }
        if (vv.y > 0.f) { int p = atomicAdd(cnt, 1); if (p < MAXD) nr[p] = idx * 4 + 1; }
        if (vv.z > 0.f) { int p = atomicAdd(cnt, 1); if (p < MAXD) nr[p] = idx * 4 + 2; }
        if (vv.w > 0.f) { int p = atomicAdd(cnt, 1); if (p < MAXD) nr[p] = idx * 4 + 3; }
    }
    __syncthreads();
    int c = *cnt; if (c > MAXD) c = MAXD;
    if (t == 0) deg[row] = c;
    // zero-pad tail so attn reads j-groups unconditionally (padded edges get
    // p=-1e30 -> w=exp2(-1e30)=0, contribution exactly 0)
    if (t < MAXD && t >= c) nr[t] = 0;
}

// ============================================================ qkv bf16 MFMA
// qk[16384 x 384] f32 = hB @ Wpt^T. cols [0,64) = q (pre-scaled by log2e for
// exp2-softmax), [64,128) = k, [128,384) = v. Block: 64 rows x 128 cols,
// 4 waves. Verified 16x16x32 layout: A[m=lane&15][k=quad*8+j],
// B[k=quad*8+j][n=lane&15], C/D col=lane&15 row=quad*4+reg.
__global__ __launch_bounds__(256) void k_qkv_mfma(const u16* __restrict__ hB,
                                                  const u16* __restrict__ Wpt,
                                                  float* __restrict__ qk) {
    __shared__ u16 As[64 * 40];    // stride 40 bf16 = 80B (16B-aligned, depowered)
    __shared__ u16 Bs[128 * 40];
    int t = threadIdx.x;
    // XCD-batch swizzle: 768 blocks = 96/XCD; XCD c -> row-blocks of batch c
    int flat = blockIdx.x + blockIdx.y * 3;
    int v = ((flat & 7) * 96) + (flat >> 3);
    int col0 = (v % 3) * 128, row0 = (v / 3) * 64;
    int wave = t >> 6, lane = t & 63;
    int l16 = lane & 15, quad = lane >> 4;

    f4 acc[4][2];
#pragma unroll
    for (int i = 0; i < 4; ++i) { acc[i][0] = (f4){0,0,0,0}; acc[i][1] = (f4){0,0,0,0}; }

    int ar = t >> 2, ao = (t & 3) * 8;    // A staging: row ar, 8 bf16 @ ao
    int bc = t >> 1, bo = (t & 1) * 16;   // B staging: col bc, 16 bf16 @ bo
    const u16* aP = hB  + (size_t)(row0 + ar) * 256 + ao;
    const u16* bP = Wpt + (size_t)(col0 + bc) * 256 + bo;

    us8 av  = *(const us8*)(aP);
    us8 bv0 = *(const us8*)(bP);
    us8 bv1 = *(const us8*)(bP + 8);

#pragma unroll
    for (int kc = 0; kc < 256; kc += 32) {
        __syncthreads();                    // prior iter's frag reads done
        *(us8*)&As[ar * 40 + ao] = av;
        *(us8*)&Bs[bc * 40 + bo] = bv0;
        *(us8*)&Bs[bc * 40 + bo + 8] = bv1;
        __syncthreads();
        if (kc + 32 < 256) {               // prefetch next K-step under compute
            av  = *(const us8*)(aP + kc + 32);
            bv0 = *(const us8*)(bP + kc + 32);
            bv1 = *(const us8*)(bP + kc + 40);
        }
        bf8 afr[4], bfr[2];
#pragma unroll
        for (int mt = 0; mt < 4; ++mt)
            afr[mt] = *(bf8*)&As[(mt * 16 + l16) * 40 + quad * 8];
#pragma unroll
        for (int nt = 0; nt < 2; ++nt)
            bfr[nt] = *(bf8*)&Bs[((wave * 2 + nt) * 16 + l16) * 40 + quad * 8];
#pragma unroll
        for (int mt = 0; mt < 4; ++mt)
#pragma unroll
            for (int nt = 0; nt < 2; ++nt)
                acc[mt][nt] = __builtin_amdgcn_mfma_f32_16x16x32_bf16(
                    afr[mt], bfr[nt], acc[mt][nt], 0, 0, 0);
    }
#pragma unroll
    for (int mt = 0; mt < 4; ++mt)
#pragma unroll
        for (int nt = 0; nt < 2; ++nt) {
            int c = col0 + (wave * 2 + nt) * 16 + l16;
#pragma unroll
            for (int reg = 0; reg < 4; ++reg) {
                int r = row0 + mt * 16 + quad * 4 + reg;
                float val = acc[mt][nt][reg];
                if (c < 64) val *= 1.44269504f;   // log2(e): exp(p)=exp2(p*log2e)
                qk[(size_t)r * 384 + c] = val;
            }
        }
}

// ========================================================= sparse attention
// One wave per row; 4 edges/iter, quad g owns edge e+g. R7: all-f32 gathers,
// no online max (w=exp2(p), q pre-scaled), 1 exp/group (w exchanged via 3
// shfl_xor; quad-relative (w,v) pairing is order-invariant in the sums).
template <bool WRITE_OUT>
__global__ __launch_bounds__(256) void k_attn(const float* __restrict__ qk,
                                              const int* __restrict__ deg,
                                              const int* __restrict__ nbr,
                                              const float* __restrict__ gcb,
                                              const float* __restrict__ Wc,
                                              const float* __restrict__ bc,
                                              u16* __restrict__ hB,
                                              float* __restrict__ out) {
    int wave = threadIdx.x >> 6;
    int lane = threadIdx.x & 63;
    // XCD-batch swizzle: 4096 blocks = 512/XCD = one batch per XCD
    int bid = blockIdx.x;
    int vb = ((bid & 7) << 9) + (bid >> 3);
    int row = vb * 4 + wave;
    int d = deg[row];
    int l16 = lane & 15;
    int g = lane >> 4;
    f4 g4 = *(const f4*)(gcb + lane * 4);
    float h0, h1, h2, h3;
    if (d == 0) {
        h0 = sigmoidf_(g4.x); h1 = sigmoidf_(g4.y);
        h2 = sigmoidf_(g4.z); h3 = sigmoidf_(g4.w);
    } else {
        f4 q4 = *(const f4*)(qk + (size_t)row * 384 + l16 * 4);  // pre-scaled
        const int* jl = nbr + (size_t)row * MAXD;
        const float* kvb = qk + (size_t)(row & ~(NN - 1)) * 384; // batch base
        int gx1 = g ^ 1, gx2 = g ^ 2, gx3 = g ^ 3;               // hoisted
        float s = 0.f;
        f4 a = {0, 0, 0, 0};
        // group-0 preload
        int j0 = jl[g], j1 = jl[gx1], j2 = jl[gx2], j3 = jl[gx3];
        f4 kq = *(const f4*)(kvb + (size_t)j0 * 384 + 64 + l16 * 4);
        for (int e = 0; e < d; e += 4) {
            // prefetch next group's indices + own quad's k row
            int en = (e + 4 < d) ? (e + 4) : 0;
            int j0n = jl[en + g],   j1n = jl[en + gx1];
            int j2n = jl[en + gx2], j3n = jl[en + gx3];
            f4 kqn = *(const f4*)(kvb + (size_t)j0n * 384 + 64 + l16 * 4);
            // v gathers (quad-relative row order), fly under the logit reduce
            f4 u0 = *(const f4*)(kvb + (size_t)j0 * 384 + 128 + lane * 4);
            f4 u1 = *(const f4*)(kvb + (size_t)j1 * 384 + 128 + lane * 4);
            f4 u2 = *(const f4*)(kvb + (size_t)j2 * 384 + 128 + lane * 4);
            f4 u3 = *(const f4*)(kvb + (size_t)j3 * 384 + 128 + lane * 4);
            // own quad's logit (pre-scaled by log2e via q)
            float p = q4.x * kq.x + q4.y * kq.y + q4.z * kq.z + q4.w * kq.w;
            p += __shfl_xor(p, 1); p += __shfl_xor(p, 2);
            p += __shfl_xor(p, 4); p += __shfl_xor(p, 8);
            if (e + g >= d) p = -1e30f;
            float w = __builtin_amdgcn_exp2f(p);   // padded edge -> 0
            float wa = __shfl_xor(w, 16);
            float wb = __shfl_xor(w, 32);
            float wc = __shfl_xor(wa, 32);
            s += (w + wa) + (wb + wc);
            a.x += w * u0.x + wa * u1.x + wb * u2.x + wc * u3.x;
            a.y += w * u0.y + wa * u1.y + wb * u2.y + wc * u3.y;
            a.z += w * u0.z + wa * u1.z + wb * u2.z + wc * u3.z;
            a.w += w * u0.w + wa * u1.w + wb * u2.w + wc * u3.w;
            j0 = j0n; j1 = j1n; j2 = j2n; j3 = j3n; kq = kqn;
        }
        float inv = 1.f / s;
        h0 = sigmoidf_(a.x * inv + g4.x);
        h1 = sigmoidf_(a.y * inv + g4.y);
        h2 = sigmoidf_(a.z * inv + g4.z);
        h3 = sigmoidf_(a.w * inv + g4.w);
    }
    if (!WRITE_OUT) {
        us4 o;
        o.x = f2bf(h0); o.y = f2bf(h1); o.z = f2bf(h2); o.w = f2bf(h3);
        *(us4*)(hB + (size_t)row * 256 + lane * 4) = o;
    } else {
        // classifier head: lane owns cols 4l..4l+3; Wc is [256][2]
        f4 wc0 = *(const f4*)(Wc + lane * 8);
        f4 wc1 = *(const f4*)(Wc + lane * 8 + 4);
        float pa = h0 * wc0.x + h1 * wc0.z + h2 * wc1.x + h3 * wc1.z;
        float pb = h0 * wc0.y + h1 * wc0.w + h2 * wc1.y + h3 * wc1.w;
#pragma unroll
        for (int off = 32; off; off >>= 1) {
            pa += __shfl_xor(pa, off);
            pb += __shfl_xor(pb, off);
        }
        if (lane == 0) {
            float l0 = pa + bc[0], l1 = pb + bc[1];
            float mx = fmaxf(l0, l1);
            float e0 = __expf(l0 - mx), e1 = __expf(l1 - mx);
            float inv = 1.f / (e0 + e1);
            out[(size_t)row * 2 + 0] = e0 * inv;
            out[(size_t)row * 2 + 1] = e1 * inv;
        }
    }
}

extern "C" void kernel_launch(void* const* d_in, const int* in_sizes, int n_in,
                              void* d_out, int out_size, void* d_ws, size_t ws_size,
                              hipStream_t stream) {
    const int*   x    = (const int*)d_in[0];
    const int*   cue  = (const int*)d_in[1];
    const float* adj  = (const float*)d_in[2];
    const float* emb  = (const float*)d_in[3];
    const float* Wh   = (const float*)d_in[4];
    const float* bh   = (const float*)d_in[5];
    const float* Wq   = (const float*)d_in[6];
    const float* Wk   = (const float*)d_in[7];
    const float* Wv   = (const float*)d_in[8];
    const float* gcb  = (const float*)d_in[9];
    const float* Wc   = (const float*)d_in[10];
    const float* bc   = (const float*)d_in[11];
    float* out = (float*)d_out;

    // workspace carve (~37.4 MB)
    char* w = (char*)d_ws;
    u16*   hB  = (u16*)w;                 w += (size_t)ROWS * 256 * 2;   // 8 MB
    float* qk  = (float*)w;               w += (size_t)ROWS * 384 * 4;   // 25.2 MB
    u16*   Wpt = (u16*)w;                 w += (size_t)384 * 256 * 2;    // 192 KB
    int*   deg = (int*)w;                 w += (size_t)ROWS * 4;         // 64 KB
    int*   nbr = (int*)w;                                                // 4 MB

    // pack + embed GEMM + csr scan (VALU work hides under 134MB adj read)
    k_fused_front<<<PACK_BLKS + EMB_BLKS + ROWS, 256, 0, stream>>>(
        x, cue, adj, emb, Wh, bh, Wq, Wk, Wv, hB, Wpt, deg, nbr);
    // layer 1
    k_qkv_mfma<<<dim3(3, ROWS / 64), 256, 0, stream>>>(hB, Wpt, qk);
    k_attn<false><<<ROWS / 4, 256, 0, stream>>>(qk, deg, nbr, gcb, Wc, bc, hB, out);
    // layer 2 (+ fused classifier head)
    k_qkv_mfma<<<dim3(3, ROWS / 64), 256, 0, stream>>>(hB, Wpt, qk);
    k_attn<true><<<ROWS / 4, 256, 0, stream>>>(qk, deg, nbr, gcb, Wc, bc, hB, out);
}

// Round 6
// 321.545 us; speedup vs baseline: 2.5808x; 1.0048x over previous
//
#include <hip/hip_runtime.h>
#include <hip/hip_bf16.h>

// GCN_20332375179669: 2-layer graph attention, B=8 N=2048 H=256 A=64.
// Cost model (R6 diag + R7 A/B): ~245us harness-fixed (3x 512MiB poison fills
// @80us in the timed window); front ~26us (adj HBM floor 21.3); qkv ~3.5us x2;
// attn ~21.5us x2 = max(VALU, L2-gather-bytes).
// R7 lesson: f32 kv halved VALU but DOUBLED L2 gather bytes (420MB/dispatch,
// ~12us at 34.5TB/s) -> net only -5us.
// R9 (this round): bf16 k/v storage (L2 bytes 420->210MB) + keep R7's lean
// softmax (no online max, w=exp2(p) with q pre-scaled by log2e, 1 exp/group,
// direct j loads, quad-relative w/v pairing). q stays f32.

#define NB 8
#define NN 2048
#define ROWS (NB * NN)
#define MAXD 64   // Binomial(2048,0.01): mean 20.5, sd 4.5 -> ~9.7 sigma

typedef float f4 __attribute__((ext_vector_type(4)));
typedef short bf8 __attribute__((ext_vector_type(8)));   // 8 bf16 = one MFMA frag
typedef unsigned short u16;
typedef u16 us4 __attribute__((ext_vector_type(4)));
typedef u16 us8 __attribute__((ext_vector_type(8)));

__device__ __forceinline__ float sigmoidf_(float x) { return 1.f / (1.f + __expf(-x)); }
__device__ __forceinline__ u16 f2bf(float f) {          // RNE fp32->bf16
    unsigned u = __float_as_uint(f);
    u += 0x7fffu + ((u >> 16) & 1u);
    return (u16)(u >> 16);
}
__device__ __forceinline__ float bf2f(u16 h) {
    return __uint_as_float(((unsigned)h) << 16);
}

// ============================================================== fused front
// bid < 96        : pack Wq|Wk|Wv -> Wpt[c][f] bf16 (transposed, k-contiguous)
// 96 <= bid < 608 : embed GEMM tile (fp32 compute, bf16 h output)
// bid >= 608      : csr row scan (the 134MB adj read = HBM floor)
#define PACK_BLKS 96
#define EMB_BLKS 512

__global__ __launch_bounds__(256) void k_fused_front(
        const int* __restrict__ x, const int* __restrict__ cue,
        const float* __restrict__ adj, const float* __restrict__ emb,
        const float* __restrict__ Wh, const float* __restrict__ bh,
        const float* __restrict__ Wq, const float* __restrict__ Wk,
        const float* __restrict__ Wv,
        u16* __restrict__ hB, u16* __restrict__ Wpt,
        int* __restrict__ deg, int* __restrict__ nbr) {
    __shared__ float As[32 * 64];
    __shared__ float Ws[32 * 128];
    int bid = blockIdx.x;
    int t = threadIdx.x;

    if (bid < PACK_BLKS) {
        // Wpt[c*256 + f] = bf16(W*[f][c]),  c in [0,384), f in [0,256)
        int idxp = bid * 256 + t;
#pragma unroll
        for (int r = 0; r < 4; ++r) {
            int i = idxp + r * PACK_BLKS * 256;
            int c = i >> 8, f = i & 255;
            float v;
            if (c < 64)       v = Wq[f * 64 + c];
            else if (c < 128) v = Wk[f * 64 + (c - 64)];
            else              v = Wv[f * 256 + (c - 128)];
            Wpt[i] = f2bf(v);
        }
        return;
    }

    if (bid < PACK_BLKS + EMB_BLKS) {
        // h[64 x 128 tile] = relu(F @ Wh + bh), F = [emb[x], cue]
        int rb2 = bid - PACK_BLKS;
        int v2 = ((rb2 & 7) << 6) + (rb2 >> 3);
        int rt = v2 >> 1, ct = v2 & 1;
        int row0 = rt * 64, col0 = ct * 128;
        int sm = t & 63, skg = t >> 6;
        int swc = (t & 31) * 4, swk = t >> 5;
        int tx = t & 15, ty = t >> 4;
        int xr = x[row0 + sm];
        float cv = (float)cue[row0 + sm];
        const float* er = emb + (size_t)xr * 255;

        float acc[4][8];
#pragma unroll
        for (int i = 0; i < 4; ++i)
#pragma unroll
            for (int j = 0; j < 8; ++j) acc[i][j] = 0.f;

        for (int kc = 0; kc < 256; kc += 32) {
            int kb = skg * 8;
#pragma unroll
            for (int u = 0; u < 8; ++u) {
                int f = kc + kb + u;
                As[(kb + u) * 64 + sm] = (f < 255) ? er[f] : cv;
            }
#pragma unroll
            for (int r = 0; r < 4; ++r) {
                int kk = swk + r * 8;
                f4 w = *(const f4*)(Wh + (size_t)(kc + kk) * 256 + col0 + swc);
                *(f4*)&Ws[kk * 128 + swc] = w;
            }
            __syncthreads();
#pragma unroll
            for (int k = 0; k < 32; ++k) {
                f4 av = *(f4*)&As[k * 64 + ty * 4];
                f4 w0 = *(f4*)&Ws[k * 128 + tx * 8];
                f4 w1 = *(f4*)&Ws[k * 128 + tx * 8 + 4];
                float a[4] = {av.x, av.y, av.z, av.w};
                float w[8] = {w0.x, w0.y, w0.z, w0.w, w1.x, w1.y, w1.z, w1.w};
#pragma unroll
                for (int i = 0; i < 4; ++i)
#pragma unroll
                    for (int j = 0; j < 8; ++j) acc[i][j] += a[i] * w[j];
            }
            __syncthreads();
        }
        f4 b0 = *(const f4*)(bh + col0 + tx * 8);
        f4 b1 = *(const f4*)(bh + col0 + tx * 8 + 4);
        float bb[8] = {b0.x, b0.y, b0.z, b0.w, b1.x, b1.y, b1.z, b1.w};
#pragma unroll
        for (int i = 0; i < 4; ++i) {
            int row = row0 + ty * 4 + i;
            us8 o;
#pragma unroll
            for (int j = 0; j < 8; ++j) o[j] = f2bf(fmaxf(acc[i][j] + bb[j], 0.f));
            *(us8*)(hB + (size_t)row * 256 + col0 + tx * 8) = o;
        }
        return;
    }

    // ---- csr scan (XCD-batch swizzle: rb%8 = batch, 2048 rows each)
    int rb = bid - (PACK_BLKS + EMB_BLKS);
    int row = ((rb & 7) << 11) + (rb >> 3);
    const f4* ar4 = (const f4*)(adj + (size_t)row * NN);
    int* cnt = (int*)As;
    if (t == 0) *cnt = 0;
    __syncthreads();
    int* nr = nbr + (size_t)row * MAXD;
#pragma unroll
    for (int it = 0; it < 2; ++it) {
        int idx = it * 256 + t;
        f4 vv = __builtin_nontemporal_load(ar4 + idx);
        if (vv.x > 0.f) { int p = atomicAdd(cnt, 1); if (p < MAXD) nr[p] = idx * 4 + 0; }
        if (vv.y > 0.f) { int p = atomicAdd(cnt, 1); if (p < MAXD) nr[p] = idx * 4 + 1; }
        if (vv.z > 0.f) { int p = atomicAdd(cnt, 1); if (p < MAXD) nr[p] = idx * 4 + 2; }
        if (vv.w > 0.f) { int p = atomicAdd(cnt, 1); if (p < MAXD) nr[p] = idx * 4 + 3; }
    }
    __syncthreads();
    int c = *cnt; if (c > MAXD) c = MAXD;
    if (t == 0) deg[row] = c;
    // zero-pad tail so attn reads j-groups unconditionally (padded edges get
    // p=-1e30 -> w=exp2(-1e30)=0, contribution exactly 0)
    if (t < MAXD && t >= c) nr[t] = 0;
}

// ============================================================ qkv bf16 MFMA
// hB @ Wpt^T -> q[ROWS][64] f32 (pre-scaled by log2e for exp2-softmax) and
// kv[ROWS][320] bf16 (k cols 0..63, v cols 64..319). Block: 64 rows x 128
// cols, 4 waves. Verified 16x16x32 layout: A[m=lane&15][k=quad*8+j],
// B[k=quad*8+j][n=lane&15], C/D col=lane&15 row=quad*4+reg.
__global__ __launch_bounds__(256) void k_qkv_mfma(const u16* __restrict__ hB,
                                                  const u16* __restrict__ Wpt,
                                                  float* __restrict__ q,
                                                  u16* __restrict__ kv) {
    __shared__ u16 As[64 * 40];    // stride 40 bf16 = 80B (16B-aligned, depowered)
    __shared__ u16 Bs[128 * 40];
    int t = threadIdx.x;
    // XCD-batch swizzle: 768 blocks = 96/XCD; XCD c -> row-blocks of batch c
    int flat = blockIdx.x + blockIdx.y * 3;
    int v = ((flat & 7) * 96) + (flat >> 3);
    int col0 = (v % 3) * 128, row0 = (v / 3) * 64;
    int wave = t >> 6, lane = t & 63;
    int l16 = lane & 15, quad = lane >> 4;

    f4 acc[4][2];
#pragma unroll
    for (int i = 0; i < 4; ++i) { acc[i][0] = (f4){0,0,0,0}; acc[i][1] = (f4){0,0,0,0}; }

    int ar = t >> 2, ao = (t & 3) * 8;    // A staging: row ar, 8 bf16 @ ao
    int bc = t >> 1, bo = (t & 1) * 16;   // B staging: col bc, 16 bf16 @ bo
    const u16* aP = hB  + (size_t)(row0 + ar) * 256 + ao;
    const u16* bP = Wpt + (size_t)(col0 + bc) * 256 + bo;

    us8 av  = *(const us8*)(aP);
    us8 bv0 = *(const us8*)(bP);
    us8 bv1 = *(const us8*)(bP + 8);

#pragma unroll
    for (int kc = 0; kc < 256; kc += 32) {
        __syncthreads();                    // prior iter's frag reads done
        *(us8*)&As[ar * 40 + ao] = av;
        *(us8*)&Bs[bc * 40 + bo] = bv0;
        *(us8*)&Bs[bc * 40 + bo + 8] = bv1;
        __syncthreads();
        if (kc + 32 < 256) {               // prefetch next K-step under compute
            av  = *(const us8*)(aP + kc + 32);
            bv0 = *(const us8*)(bP + kc + 32);
            bv1 = *(const us8*)(bP + kc + 40);
        }
        bf8 afr[4], bfr[2];
#pragma unroll
        for (int mt = 0; mt < 4; ++mt)
            afr[mt] = *(bf8*)&As[(mt * 16 + l16) * 40 + quad * 8];
#pragma unroll
        for (int nt = 0; nt < 2; ++nt)
            bfr[nt] = *(bf8*)&Bs[((wave * 2 + nt) * 16 + l16) * 40 + quad * 8];
#pragma unroll
        for (int mt = 0; mt < 4; ++mt)
#pragma unroll
            for (int nt = 0; nt < 2; ++nt)
                acc[mt][nt] = __builtin_amdgcn_mfma_f32_16x16x32_bf16(
                    afr[mt], bfr[nt], acc[mt][nt], 0, 0, 0);
    }
#pragma unroll
    for (int mt = 0; mt < 4; ++mt)
#pragma unroll
        for (int nt = 0; nt < 2; ++nt) {
            int c = col0 + (wave * 2 + nt) * 16 + l16;
#pragma unroll
            for (int reg = 0; reg < 4; ++reg) {
                int r = row0 + mt * 16 + quad * 4 + reg;
                float val = acc[mt][nt][reg];
                if (c < 64) q[(size_t)r * 64 + c] = val * 1.44269504f;  // log2e
                else        kv[(size_t)r * 320 + (c - 64)] = f2bf(val);
            }
        }
}

// ========================================================= sparse attention
// One wave per row; 4 edges/iter, quad g owns edge e+g. Lean softmax (R7):
// no online max (w=exp2(p), q pre-scaled), 1 exp/group, w exchanged via 3
// shfl_xor with quad-relative (w,v) pairing (order-invariant sums), direct
// jl[e+(g^0..3)] loads. R9: bf16 kv gathers (half the L2 bytes of f32).
template <bool WRITE_OUT>
__global__ __launch_bounds__(256) void k_attn(const float* __restrict__ q,
                                              const u16* __restrict__ kv,
                                              const int* __restrict__ deg,
                                              const int* __restrict__ nbr,
                                              const float* __restrict__ gcb,
                                              const float* __restrict__ Wc,
                                              const float* __restrict__ bc,
                                              u16* __restrict__ hB,
                                              float* __restrict__ out) {
    int wave = threadIdx.x >> 6;
    int lane = threadIdx.x & 63;
    // XCD-batch swizzle: 4096 blocks = 512/XCD = one batch per XCD
    int bid = blockIdx.x;
    int vb = ((bid & 7) << 9) + (bid >> 3);
    int row = vb * 4 + wave;
    int d = deg[row];
    int l16 = lane & 15;
    int g = lane >> 4;
    f4 g4 = *(const f4*)(gcb + lane * 4);
    float h0, h1, h2, h3;
    if (d == 0) {
        h0 = sigmoidf_(g4.x); h1 = sigmoidf_(g4.y);
        h2 = sigmoidf_(g4.z); h3 = sigmoidf_(g4.w);
    } else {
        f4 q4 = *(const f4*)(q + (size_t)row * 64 + l16 * 4);    // pre-scaled
        const int* jl = nbr + (size_t)row * MAXD;
        const u16* kvb = kv + (size_t)(row & ~(NN - 1)) * 320;   // batch base
        int gx1 = g ^ 1, gx2 = g ^ 2, gx3 = g ^ 3;               // hoisted
        float s = 0.f;
        f4 a = {0, 0, 0, 0};
        // group-0 preload
        int j0 = jl[g], j1 = jl[gx1], j2 = jl[gx2], j3 = jl[gx3];
        us4 kq = *(const us4*)(kvb + (size_t)j0 * 320 + l16 * 4);
        for (int e = 0; e < d; e += 4) {
            // prefetch next group's indices + own quad's k row
            int en = (e + 4 < d) ? (e + 4) : 0;
            int j0n = jl[en + g],   j1n = jl[en + gx1];
            int j2n = jl[en + gx2], j3n = jl[en + gx3];
            us4 kqn = *(const us4*)(kvb + (size_t)j0n * 320 + l16 * 4);
            // v gathers (quad-relative row order), fly under the logit reduce
            us4 u0 = *(const us4*)(kvb + (size_t)j0 * 320 + 64 + lane * 4);
            us4 u1 = *(const us4*)(kvb + (size_t)j1 * 320 + 64 + lane * 4);
            us4 u2 = *(const us4*)(kvb + (size_t)j2 * 320 + 64 + lane * 4);
            us4 u3 = *(const us4*)(kvb + (size_t)j3 * 320 + 64 + lane * 4);
            // own quad's logit (pre-scaled by log2e via q)
            float p = q4.x * bf2f(kq.x) + q4.y * bf2f(kq.y)
                    + q4.z * bf2f(kq.z) + q4.w * bf2f(kq.w);
            p += __shfl_xor(p, 1); p += __shfl_xor(p, 2);
            p += __shfl_xor(p, 4); p += __shfl_xor(p, 8);
            if (e + g >= d) p = -1e30f;
            float w = __builtin_amdgcn_exp2f(p);   // padded edge -> 0
            float wa = __shfl_xor(w, 16);
            float wb = __shfl_xor(w, 32);
            float wc = __shfl_xor(wa, 32);
            s += (w + wa) + (wb + wc);
            a.x += w * bf2f(u0.x) + wa * bf2f(u1.x) + wb * bf2f(u2.x) + wc * bf2f(u3.x);
            a.y += w * bf2f(u0.y) + wa * bf2f(u1.y) + wb * bf2f(u2.y) + wc * bf2f(u3.y);
            a.z += w * bf2f(u0.z) + wa * bf2f(u1.z) + wb * bf2f(u2.z) + wc * bf2f(u3.z);
            a.w += w * bf2f(u0.w) + wa * bf2f(u1.w) + wb * bf2f(u2.w) + wc * bf2f(u3.w);
            j0 = j0n; j1 = j1n; j2 = j2n; j3 = j3n; kq = kqn;
        }
        float inv = 1.f / s;
        h0 = sigmoidf_(a.x * inv + g4.x);
        h1 = sigmoidf_(a.y * inv + g4.y);
        h2 = sigmoidf_(a.z * inv + g4.z);
        h3 = sigmoidf_(a.w * inv + g4.w);
    }
    if (!WRITE_OUT) {
        us4 o;
        o.x = f2bf(h0); o.y = f2bf(h1); o.z = f2bf(h2); o.w = f2bf(h3);
        *(us4*)(hB + (size_t)row * 256 + lane * 4) = o;
    } else {
        // classifier head: lane owns cols 4l..4l+3; Wc is [256][2]
        f4 wc0 = *(const f4*)(Wc + lane * 8);
        f4 wc1 = *(const f4*)(Wc + lane * 8 + 4);
        float pa = h0 * wc0.x + h1 * wc0.z + h2 * wc1.x + h3 * wc1.z;
        float pb = h0 * wc0.y + h1 * wc0.w + h2 * wc1.y + h3 * wc1.w;
#pragma unroll
        for (int off = 32; off; off >>= 1) {
            pa += __shfl_xor(pa, off);
            pb += __shfl_xor(pb, off);
        }
        if (lane == 0) {
            float l0 = pa + bc[0], l1 = pb + bc[1];
            float mx = fmaxf(l0, l1);
            float e0 = __expf(l0 - mx), e1 = __expf(l1 - mx);
            float inv = 1.f / (e0 + e1);
            out[(size_t)row * 2 + 0] = e0 * inv;
            out[(size_t)row * 2 + 1] = e1 * inv;
        }
    }
}

extern "C" void kernel_launch(void* const* d_in, const int* in_sizes, int n_in,
                              void* d_out, int out_size, void* d_ws, size_t ws_size,
                              hipStream_t stream) {
    const int*   x    = (const int*)d_in[0];
    const int*   cue  = (const int*)d_in[1];
    const float* adj  = (const float*)d_in[2];
    const float* emb  = (const float*)d_in[3];
    const float* Wh   = (const float*)d_in[4];
    const float* bh   = (const float*)d_in[5];
    const float* Wq   = (const float*)d_in[6];
    const float* Wk   = (const float*)d_in[7];
    const float* Wv   = (const float*)d_in[8];
    const float* gcb  = (const float*)d_in[9];
    const float* Wc   = (const float*)d_in[10];
    const float* bc   = (const float*)d_in[11];
    float* out = (float*)d_out;

    // workspace carve (~26.3 MB)
    char* w = (char*)d_ws;
    u16*   hB  = (u16*)w;                 w += (size_t)ROWS * 256 * 2;   // 8 MB
    float* q   = (float*)w;               w += (size_t)ROWS * 64 * 4;    // 4 MB
    u16*   kv  = (u16*)w;                 w += (size_t)ROWS * 320 * 2;   // 10 MB
    u16*   Wpt = (u16*)w;                 w += (size_t)384 * 256 * 2;    // 192 KB
    int*   deg = (int*)w;                 w += (size_t)ROWS * 4;         // 64 KB
    int*   nbr = (int*)w;                                                // 4 MB

    // pack + embed GEMM + csr scan (VALU work hides under 134MB adj read)
    k_fused_front<<<PACK_BLKS + EMB_BLKS + ROWS, 256, 0, stream>>>(
        x, cue, adj, emb, Wh, bh, Wq, Wk, Wv, hB, Wpt, deg, nbr);
    // layer 1
    k_qkv_mfma<<<dim3(3, ROWS / 64), 256, 0, stream>>>(hB, Wpt, q, kv);
    k_attn<false><<<ROWS / 4, 256, 0, stream>>>(q, kv, deg, nbr, gcb, Wc, bc, hB, out);
    // layer 2 (+ fused classifier head)
    k_qkv_mfma<<<dim3(3, ROWS / 64), 256, 0, stream>>>(hB, Wpt, q, kv);
    k_attn<true><<<ROWS / 4, 256, 0, stream>>>(q, kv, deg, nbr, gcb, Wc, bc, hB, out);
}